// Round 1
// baseline (1673.163 us; speedup 1.0000x reference)
//
#include <hip/hip_runtime.h>

#define C_ 256
#define HW_ 65536
#define IMG_ (C_*HW_)

typedef __attribute__((ext_vector_type(4))) float f32x4;
typedef __attribute__((ext_vector_type(8))) short s16x8;

__device__ __forceinline__ ushort f2bf(float f) {
  union { float f; unsigned u; } v; v.f = f;
  unsigned u = v.u;
  return (ushort)((u + 0x7fffu + ((u >> 16) & 1u)) >> 16);
}

// ---------------- weight prep: fold gamma/beta/scale into bf16 weights ----------------
__global__ void k_prep(const float* __restrict__ wq, const float* __restrict__ bq,
                       const float* __restrict__ wk, const float* __restrict__ bk,
                       const float* __restrict__ wv, const float* __restrict__ bv,
                       const float* __restrict__ wo, const float* __restrict__ bo,
                       const float* __restrict__ gamma, const float* __restrict__ beta,
                       ushort* __restrict__ wqE, ushort* __restrict__ wkE,
                       ushort* __restrict__ wvE, ushort* __restrict__ woE,
                       float* __restrict__ biasAll) {
  int m = blockIdx.x, o = threadIdx.x;
  const float* W  = m==0?wq : m==1?wk : m==2?wv : wo;
  const float* bi = m==0?bq : m==1?bk : m==2?bv : bo;
  ushort* dst = m==0?wqE : m==1?wkE : m==2?wvE : woE;
  float s = (m==0) ? 0.0625f : 1.0f;   // fold attn scale 256^-0.5 into Q
  float acc = 0.f;
  for (int i=0;i<256;i++) {
    float wval = W[o*256+i];
    float g  = (m==3) ? 1.0f : gamma[i];
    float bt = (m==3) ? 0.0f : beta[i];
    acc += wval*bt;
    dst[o*256+i] = f2bf(wval*g*s);
  }
  biasAll[m*256+o] = (bi[o] + acc) * s;
}

// ---------------- group-norm stats, two stage ----------------
__global__ void k_stats1(const float* __restrict__ x, float2* __restrict__ part) {
  int bid = blockIdx.x;                  // 1024 = 128 (b,g) * 8 chunks
  int tid = threadIdx.x;
  const f32x4* p = (const f32x4*)(x + (size_t)bid*65536);
  float s = 0.f, ss = 0.f;
  #pragma unroll 4
  for (int i = tid; i < 16384; i += 256) {
    f32x4 v = p[i];
    s  += v[0]+v[1]+v[2]+v[3];
    ss += v[0]*v[0]+v[1]*v[1]+v[2]*v[2]+v[3]*v[3];
  }
  __shared__ float sa[256], sb[256];
  sa[tid]=s; sb[tid]=ss; __syncthreads();
  for (int k=128;k>0;k>>=1){
    if (tid<k){ sa[tid]+=sa[tid+k]; sb[tid]+=sb[tid+k]; }
    __syncthreads();
  }
  if (tid==0) part[bid] = make_float2(sa[0], sb[0]);
}

__global__ void k_stats2(const float2* __restrict__ part, float2* __restrict__ stats) {
  int bg = threadIdx.x;   // 128
  float s=0.f, ss=0.f;
  for (int j=0;j<8;j++){ float2 v = part[bg*8+j]; s+=v.x; ss+=v.y; }
  float mean = s * (1.f/524288.f);
  float var  = ss * (1.f/524288.f) - mean*mean;
  stats[bg] = make_float2(mean, rsqrtf(var + 1e-6f));
}

// ---------------- fused GN-normalize + QKV projection ----------------
// mat=0: Qt[win][t][c] (A=xn^T col-read, B=wqE row-read), mat=1: Kt[win][t][c],
// mat=2: V[win][c][t]  (A=wvE row-read, B=xn^T col-read)
__global__ __launch_bounds__(512) void k_qkv(const float* __restrict__ x,
    const float2* __restrict__ stats,
    const ushort* __restrict__ wqE, const ushort* __restrict__ wkE,
    const ushort* __restrict__ wvE, const float* __restrict__ biasAll,
    ushort* __restrict__ Qt, ushort* __restrict__ Kt, ushort* __restrict__ V) {
  int mat = blockIdx.x;
  int w = blockIdx.y;
  int b = w >> 8, wy = (w >> 4) & 15, wx = w & 15;
  int tid = threadIdx.x, l = tid & 63, wid = tid >> 6, h = l >> 4;
  __shared__ __align__(16) ushort temp[32][270];   // xn chunk [ci][t], 540B rows
  __shared__ __align__(16) ushort wlds[256][40];   // weight chunk [o][ci], 80B rows
  const ushort* wsrc = (mat==0) ? wqE : (mat==1) ? wkE : wvE;
  const float* xbase = x + (size_t)b*IMG_ + wy*16*256 + wx*16;

  f32x4 acc[32];
  #pragma unroll
  for (int i=0;i<32;i++) acc[i] = (f32x4){0.f,0.f,0.f,0.f};

  int kh = h*8;
  for (int ck=0; ck<8; ck++) {
    int cb = ck*32;
    __syncthreads();
    // stage normalized x chunk (32 ch x 256 tok)
    #pragma unroll
    for (int r=0;r<4;r++) {
      int s2 = tid + 512*r;
      int cl = s2 >> 6, slot = s2 & 63;
      int ty = slot >> 2, tx4 = slot & 3;
      f32x4 v = *(const f32x4*)(xbase + (size_t)(cb+cl)*HW_ + ty*256 + tx4*4);
      float2 st = stats[b*32 + ((cb+cl)>>3)];
      unsigned p0 = (unsigned)f2bf((v[0]-st.x)*st.y) | ((unsigned)f2bf((v[1]-st.x)*st.y) << 16);
      unsigned p1 = (unsigned)f2bf((v[2]-st.x)*st.y) | ((unsigned)f2bf((v[3]-st.x)*st.y) << 16);
      unsigned* dp = (unsigned*)&temp[cl][ty*16 + tx4*4];
      dp[0] = p0; dp[1] = p1;
    }
    // stage weight chunk (256 o x 32 ci)
    #pragma unroll
    for (int r=0;r<2;r++) {
      int s2 = tid + 512*r;
      int o = s2 >> 2, seg = s2 & 3;
      *(uint4*)&wlds[o][seg*8] = *(const uint4*)(wsrc + o*256 + cb + seg*8);
    }
    __syncthreads();
    if (mat < 2) {
      int mbase = (wid & 3) * 64;           // t dim
      int nbase = (wid >> 2) * 128;         // co dim
      s16x8 af[4];
      #pragma unroll
      for (int ms=0;ms<4;ms++) {
        int t = mbase + ms*16 + (l & 15);
        s16x8 a;
        #pragma unroll
        for (int i=0;i<8;i++) a[i] = (short)temp[kh+i][t];
        af[ms] = a;
      }
      #pragma unroll
      for (int ns=0;ns<8;ns++) {
        s16x8 bf = *(const s16x8*)&wlds[nbase + ns*16 + (l&15)][kh];
        #pragma unroll
        for (int ms=0;ms<4;ms++)
          acc[ms*8+ns] = __builtin_amdgcn_mfma_f32_16x16x32_bf16(af[ms], bf, acc[ms*8+ns], 0,0,0);
      }
    } else {
      int mbase = (wid >> 2) * 128;         // o dim
      int nbase = (wid & 3) * 64;           // t dim
      s16x8 bfv[4];
      #pragma unroll
      for (int ns=0;ns<4;ns++) {
        int t = nbase + ns*16 + (l & 15);
        s16x8 bb;
        #pragma unroll
        for (int i=0;i<8;i++) bb[i] = (short)temp[kh+i][t];
        bfv[ns] = bb;
      }
      #pragma unroll
      for (int ms=0;ms<8;ms++) {
        s16x8 a = *(const s16x8*)&wlds[mbase + ms*16 + (l&15)][kh];
        #pragma unroll
        for (int ns=0;ns<4;ns++)
          acc[ms*4+ns] = __builtin_amdgcn_mfma_f32_16x16x32_bf16(a, bfv[ns], acc[ms*4+ns], 0,0,0);
      }
    }
  }
  // epilogue
  if (mat < 2) {
    int mbase = (wid & 3) * 64, nbase = (wid >> 2) * 128;
    ushort* dst = ((mat==0) ? Qt : Kt) + (size_t)w*65536;
    const float* bs = biasAll + mat*256;
    float bl[8];
    #pragma unroll
    for (int ns=0;ns<8;ns++) bl[ns] = bs[nbase + ns*16 + (l&15)];
    #pragma unroll
    for (int ms=0;ms<4;ms++)
      #pragma unroll
      for (int j=0;j<4;j++) {
        int t = mbase + ms*16 + 4*h + j;
        #pragma unroll
        for (int ns=0;ns<8;ns++) {
          int co = nbase + ns*16 + (l&15);
          dst[t*256 + co] = f2bf(acc[ms*8+ns][j] + bl[ns]);
        }
      }
  } else {
    int mbase = (wid >> 2) * 128, nbase = (wid & 3) * 64;
    ushort* dst = V + (size_t)w*65536;
    const float* bs = biasAll + 2*256;
    #pragma unroll
    for (int ms=0;ms<8;ms++) {
      f32x4 b4 = *(const f32x4*)&bs[mbase + ms*16 + 4*h];
      #pragma unroll
      for (int j=0;j<4;j++) {
        int o = mbase + ms*16 + 4*h + j;
        #pragma unroll
        for (int ns=0;ns<4;ns++) {
          int t = nbase + ns*16 + (l&15);
          dst[o*256 + t] = f2bf(acc[ms*4+ns][j] + b4[j]);
        }
      }
    }
  }
}

// ---------------- windowed attention: S = Qt*K^T (via Kt), softmax, O^T = P*V^T ----------------
__global__ __launch_bounds__(256) void k_attn(const ushort* __restrict__ Qt,
    const ushort* __restrict__ Kt, const ushort* __restrict__ V,
    ushort* __restrict__ AO) {
  int qt = blockIdx.x, w = blockIdx.y;
  int q0 = qt * 64;
  int tid = threadIdx.x, l = tid & 63, wid = tid >> 6, h = l >> 4;
  __shared__ __align__(16) ushort Aq[64][40];
  __shared__ __align__(16) ushort BKV[256][40];
  __shared__ __align__(16) ushort P[64][280];     // 560B rows
  __shared__ float red[2][4][64];
  const ushort* qbase = Qt + (size_t)w*65536;
  const ushort* kbase = Kt + (size_t)w*65536;
  const ushort* vbase = V  + (size_t)w*65536;
  int nbase = wid * 64;
  int kh = h * 8;

  f32x4 accS[4][4];
  #pragma unroll
  for (int a=0;a<4;a++)
    #pragma unroll
    for (int bq_=0;bq_<4;bq_++) accS[a][bq_] = (f32x4){0.f,0.f,0.f,0.f};

  for (int ck=0; ck<8; ck++) {
    __syncthreads();
    { int r = tid >> 2, seg = tid & 3;
      *(uint4*)&Aq[r][seg*8] = *(const uint4*)(qbase + (q0+r)*256 + ck*32 + seg*8); }
    #pragma unroll
    for (int it=0; it<4; it++) {
      int s2 = tid + 256*it, r = s2 >> 2, seg = s2 & 3;
      *(uint4*)&BKV[r][seg*8] = *(const uint4*)(kbase + r*256 + ck*32 + seg*8);
    }
    __syncthreads();
    s16x8 af[4];
    #pragma unroll
    for (int ms=0;ms<4;ms++) af[ms] = *(const s16x8*)&Aq[ms*16 + (l&15)][kh];
    #pragma unroll
    for (int ns=0;ns<4;ns++) {
      s16x8 bf = *(const s16x8*)&BKV[nbase + ns*16 + (l&15)][kh];
      #pragma unroll
      for (int ms=0;ms<4;ms++)
        accS[ms][ns] = __builtin_amdgcn_mfma_f32_16x16x32_bf16(af[ms], bf, accS[ms][ns], 0,0,0);
    }
  }

  // ---- softmax over k (rows = q), cross-wave via LDS partials ----
  float mx[4][4];
  #pragma unroll
  for (int ms=0;ms<4;ms++)
    #pragma unroll
    for (int j=0;j<4;j++) {
      float m_ = fmaxf(fmaxf(accS[ms][0][j], accS[ms][1][j]),
                       fmaxf(accS[ms][2][j], accS[ms][3][j]));
      #pragma unroll
      for (int msk=1; msk<16; msk<<=1) m_ = fmaxf(m_, __shfl_xor(m_, msk));
      mx[ms][j] = m_;
    }
  if ((l & 15) == 0) {
    #pragma unroll
    for (int ms=0;ms<4;ms++)
      #pragma unroll
      for (int j=0;j<4;j++) red[0][wid][ms*16 + 4*h + j] = mx[ms][j];
  }
  __syncthreads();
  float sj[4][4];
  #pragma unroll
  for (int ms=0;ms<4;ms++)
    #pragma unroll
    for (int j=0;j<4;j++) {
      int row = ms*16 + 4*h + j;
      float g = fmaxf(fmaxf(red[0][0][row], red[0][1][row]),
                      fmaxf(red[0][2][row], red[0][3][row]));
      float s_ = 0.f;
      #pragma unroll
      for (int ns=0;ns<4;ns++) {
        float p = __expf(accS[ms][ns][j] - g);
        accS[ms][ns][j] = p;
        s_ += p;
      }
      #pragma unroll
      for (int msk=1; msk<16; msk<<=1) s_ += __shfl_xor(s_, msk);
      sj[ms][j] = s_;
    }
  if ((l & 15) == 0) {
    #pragma unroll
    for (int ms=0;ms<4;ms++)
      #pragma unroll
      for (int j=0;j<4;j++) red[1][wid][ms*16 + 4*h + j] = sj[ms][j];
  }
  __syncthreads();
  float rinv[4][4];
  #pragma unroll
  for (int ms=0;ms<4;ms++)
    #pragma unroll
    for (int j=0;j<4;j++) {
      int row = ms*16 + 4*h + j;
      rinv[ms][j] = 1.f / (red[1][0][row]+red[1][1][row]+red[1][2][row]+red[1][3][row]);
    }
  // write unnormalized P (bf16); normalization deferred to epilogue
  #pragma unroll
  for (int ms=0;ms<4;ms++)
    #pragma unroll
    for (int j=0;j<4;j++)
      #pragma unroll
      for (int ns=0;ns<4;ns++)
        P[ms*16 + 4*h + j][nbase + ns*16 + (l&15)] = f2bf(accS[ms][ns][j]);

  // ---- PV: O^T[q][c] = sum_k P[q][k] * V[c][k] ----
  f32x4 accO[4][4];
  #pragma unroll
  for (int a=0;a<4;a++)
    #pragma unroll
    for (int bq_=0;bq_<4;bq_++) accO[a][bq_] = (f32x4){0.f,0.f,0.f,0.f};

  for (int kt=0; kt<8; kt++) {
    __syncthreads();
    #pragma unroll
    for (int it=0; it<4; it++) {
      int s2 = tid + 256*it, r = s2 >> 2, seg = s2 & 3;
      *(uint4*)&BKV[r][seg*8] = *(const uint4*)(vbase + r*256 + kt*32 + seg*8);
    }
    __syncthreads();
    s16x8 ap[4];
    #pragma unroll
    for (int ms=0;ms<4;ms++)
      ap[ms] = *(const s16x8*)&P[ms*16 + (l&15)][kt*32 + kh];
    #pragma unroll
    for (int ns=0;ns<4;ns++) {
      s16x8 bf = *(const s16x8*)&BKV[nbase + ns*16 + (l&15)][kh];
      #pragma unroll
      for (int ms=0;ms<4;ms++)
        accO[ms][ns] = __builtin_amdgcn_mfma_f32_16x16x32_bf16(ap[ms], bf, accO[ms][ns], 0,0,0);
    }
  }
  ushort* aob = AO + (size_t)w*65536;
  #pragma unroll
  for (int ms=0;ms<4;ms++)
    #pragma unroll
    for (int j=0;j<4;j++) {
      int q = q0 + ms*16 + 4*h + j;
      float rv = rinv[ms][j];
      #pragma unroll
      for (int ns=0;ns<4;ns++)
        aob[q*256 + nbase + ns*16 + (l&15)] = f2bf(accO[ms][ns][j] * rv);
    }
}

// ---------------- output projection + residual ----------------
__global__ __launch_bounds__(512) void k_oproj(const float* __restrict__ x,
    const ushort* __restrict__ AO, const ushort* __restrict__ woE,
    const float* __restrict__ biasAll, float* __restrict__ y) {
  int w = blockIdx.x;
  int b = w >> 8, wy = (w >> 4) & 15, wx = w & 15;
  int tid = threadIdx.x, l = tid & 63, wid = tid >> 6, h = l >> 4;
  __shared__ __align__(16) ushort alds[256][40];
  __shared__ __align__(16) ushort wlds[256][40];
  const ushort* abase = AO + (size_t)w*65536;

  f32x4 acc[32];
  #pragma unroll
  for (int i=0;i<32;i++) acc[i] = (f32x4){0.f,0.f,0.f,0.f};
  int mbase = (wid >> 2) * 128, nbase = (wid & 3) * 64;
  int kh = h*8;

  for (int ck=0; ck<8; ck++) {
    __syncthreads();
    #pragma unroll
    for (int r=0;r<2;r++) {
      int s2 = tid + 512*r;
      int o = s2 >> 2, seg = s2 & 3;
      *(uint4*)&wlds[o][seg*8] = *(const uint4*)(woE + o*256 + ck*32 + seg*8);
      *(uint4*)&alds[o][seg*8] = *(const uint4*)(abase + o*256 + ck*32 + seg*8);
    }
    __syncthreads();
    s16x8 bfv[4];
    #pragma unroll
    for (int ns=0;ns<4;ns++)
      bfv[ns] = *(const s16x8*)&alds[nbase + ns*16 + (l&15)][kh];
    #pragma unroll
    for (int ms=0;ms<8;ms++) {
      s16x8 a = *(const s16x8*)&wlds[mbase + ms*16 + (l&15)][kh];
      #pragma unroll
      for (int ns=0;ns<4;ns++)
        acc[ms*4+ns] = __builtin_amdgcn_mfma_f32_16x16x32_bf16(a, bfv[ns], acc[ms*4+ns], 0,0,0);
    }
  }
  const float* bs = biasAll + 3*256;
  const float* xbase = x + (size_t)b*IMG_ + wy*16*256 + wx*16;
  float* ybase = y + (size_t)b*IMG_ + wy*16*256 + wx*16;
  #pragma unroll
  for (int ms=0;ms<8;ms++) {
    f32x4 b4 = *(const f32x4*)&bs[mbase + ms*16 + 4*h];
    #pragma unroll
    for (int j=0;j<4;j++) {
      int o = mbase + ms*16 + 4*h + j;
      #pragma unroll
      for (int ns=0;ns<4;ns++) {
        int t = nbase + ns*16 + (l&15);
        int py = t >> 4, px = t & 15;
        size_t off = (size_t)o*HW_ + py*256 + px;
        ybase[off] = xbase[off] + acc[ms*4+ns][j] + b4[j];
      }
    }
  }
}

extern "C" void kernel_launch(void* const* d_in, const int* in_sizes, int n_in,
                              void* d_out, int out_size, void* d_ws, size_t ws_size,
                              hipStream_t stream) {
  const float* x     = (const float*)d_in[0];
  const float* gamma = (const float*)d_in[1];
  const float* beta  = (const float*)d_in[2];
  const float* wq = (const float*)d_in[3];
  const float* bq = (const float*)d_in[4];
  const float* wk = (const float*)d_in[5];
  const float* bk = (const float*)d_in[6];
  const float* wv = (const float*)d_in[7];
  const float* bv = (const float*)d_in[8];
  const float* wo = (const float*)d_in[9];
  const float* bo = (const float*)d_in[10];
  float* y = (float*)d_out;
  char* ws = (char*)d_ws;

  float2* part   = (float2*)ws;                       // 8 KB
  float2* stats  = (float2*)(ws + 8192);              // 1 KB
  float*  biasAll= (float*)(ws + 9216);               // 4 KB
  ushort* wqE = (ushort*)(ws + 13312);
  ushort* wkE = (ushort*)(ws + 13312 + 131072);
  ushort* wvE = (ushort*)(ws + 13312 + 2*131072);
  ushort* woE = (ushort*)(ws + 13312 + 3*131072);
  ushort* Qt  = (ushort*)(ws + 13312 + 4*131072);     // 134 MB; also reused as AO
  // Kt and V live in d_out (exactly 2*134MB); both dead before k_oproj writes y.
  ushort* Kt = (ushort*)d_out;
  ushort* V  = (ushort*)d_out + (size_t)67108864;

  k_prep<<<4, 256, 0, stream>>>(wq,bq,wk,bk,wv,bv,wo,bo,gamma,beta,wqE,wkE,wvE,woE,biasAll);
  k_stats1<<<1024, 256, 0, stream>>>(x, part);
  k_stats2<<<1, 128, 0, stream>>>(part, stats);
  k_qkv<<<dim3(3,1024), 512, 0, stream>>>(x, stats, wqE, wkE, wvE, biasAll, Qt, Kt, V);
  k_attn<<<dim3(4,1024), 256, 0, stream>>>(Qt, Kt, V, Qt /*AO aliases Qt: disjoint q-rows*/);
  k_oproj<<<1024, 512, 0, stream>>>(x, Qt /*AO*/, woE, biasAll, y);
}